// Round 8
// baseline (28.231 us; speedup 1.0000x reference)
//
#include <hip/hip_runtime.h>
#include <math.h>

// Problem constants (from reference setup): B=4, N=65536, M=128.
#define NPTS  65536
#define MBOX  128
#define TPB   256
#define PPT   2               // points per thread
#define PPB   (TPB * PPT)     // 512 points per block

typedef float f32x16 __attribute__((ext_vector_type(16)));

// Atomic load+wait (R5-proven, absmax=0): both s_load_dwordx16 AND the
// lgkmcnt(0) wait in ONE asm statement -> SGPR outputs are genuinely valid
// when the asm retires; no window for regalloc to copy in-flight registers
// (R4's failure mode). No "memory" clobber: the asm only reads the prep
// table (written by a prior kernel, never touched by C code here), and all
// consumers are data-dependent on the outputs -> compiler may freely
// interleave surrounding VALU, volatile keeps asm order.
#define SLOADCHUNK(q0, q1, base) \
    asm volatile("s_load_dwordx16 %0, %2, 0x0\n\t" \
                 "s_load_dwordx16 %1, %2, 0x40\n\t" \
                 "s_waitcnt lgkmcnt(0)" \
                 : "=&s"(q0), "=&s"(q1) : "s"(base))

// Prep: per-box record {cx,cy,cz,hx,hy,hz,cos,sin} -> d_ws (global) for the
// main kernel's s_loads. Accurate sinf/cosf matches numpy (absmax=0, R1-R7).
__global__ __launch_bounds__(256) void prep_boxes(const float* __restrict__ boxes,
                                                  float* __restrict__ prep,
                                                  int total) {
    int i = blockIdx.x * 256 + threadIdx.x;
    if (i >= total) return;
    const float* bx = boxes + (size_t)i * 7;
    float rz = bx[6];
    float* o = prep + (size_t)i * 8;
    o[0] = bx[0];          // cx
    o[1] = bx[1];          // cy
    o[2] = bx[2];          // cz
    o[3] = 0.5f * bx[3];   // hx (exact, matches ref dims*0.5)
    o[4] = 0.5f * bx[4];   // hy
    o[5] = 0.5f * bx[5];   // hz
    o[6] = cosf(rz);
    o[7] = sinf(rz);
}

// Main: PPT=2, 512 blocks = 2 blocks/CU = 8 waves/CU = 2 waves/SIMD.
// Box records arrive via the SMEM pipe into SGPRs (4 boxes per atomic
// load+wait chunk) — ZERO LDS and ZERO per-lane VMEM in the main loop, so
// the LDS-broadcast cost that bound R2/R3/R7 (~24cyc per uniform
// ds_read_b128, scaling with wave count) is gone entirely. Per chunk:
// ~208 cyc VALU (4 boxes x 2 points) vs ~100 cyc K$-hit wait; 2 waves/SIMD
// cover each other's waits -> VALU-bound at ~13.3k cyc/SIMD ~= 5.5us.
// Descending m + overwrite: last write at smallest m == first containing
// box (reference argmax-first semantics).
// __f*_rn blocks fp-contract (mul, mul, add — no fma): absmax=0 in R1-R7.
__global__ __launch_bounds__(256) void pib_main(const float* __restrict__ points,
                                                const float* __restrict__ prep,
                                                float* __restrict__ out) {
    const int blocksPerBatch = NPTS / PPB;        // 128
    int b   = blockIdx.x >> 7;
    int blk = blockIdx.x & 127;
    size_t p0 = (size_t)b * NPTS + (size_t)blk * PPB + (size_t)threadIdx.x * PPT;

    const float* p = points + p0 * 3;             // 24 B/thread, 8 B aligned
    float2 a01 = *(const float2*)(p);
    float2 a23 = *(const float2*)(p + 2);
    float2 a45 = *(const float2*)(p + 4);
    float px0 = a01.x, py0 = a01.y, pz0 = a23.x;
    float px1 = a23.y, py1 = a45.x, pz1 = a45.y;

    const float* bb = prep + (size_t)b * (MBOX * 8);

    int idx0 = -1, idx1 = -1;

    // One box (record at q[off..off+7], off literal 0/8) against both points.
    auto test1 = [&](const f32x16& q, int off, int m) {
        float cx = q[off + 0], cy = q[off + 1], cz = q[off + 2], hx = q[off + 3];
        float hy = q[off + 4], hz = q[off + 5], cr = q[off + 6], sr = q[off + 7];
        {
            float lx = __fsub_rn(px0, cx);
            float ly = __fsub_rn(py0, cy);
            float lz = __fsub_rn(pz0, cz);
            float X = __fadd_rn(__fmul_rn(lx, cr), __fmul_rn(ly, sr));
            float Y = __fsub_rn(__fmul_rn(ly, cr), __fmul_rn(lx, sr));  // == -lx*sr+ly*cr
            bool in = (fabsf(X) <= hx) & (fabsf(Y) <= hy) & (fabsf(lz) <= hz);
            idx0 = in ? m : idx0;
        }
        {
            float lx = __fsub_rn(px1, cx);
            float ly = __fsub_rn(py1, cy);
            float lz = __fsub_rn(pz1, cz);
            float X = __fadd_rn(__fmul_rn(lx, cr), __fmul_rn(ly, sr));
            float Y = __fsub_rn(__fmul_rn(ly, cr), __fmul_rn(lx, sr));
            bool in = (fabsf(X) <= hx) & (fabsf(Y) <= hy) & (fabsf(lz) <= hz);
            idx1 = in ? m : idx1;
        }
    };

    for (int c = MBOX / 4 - 1; c >= 0; --c) {     // 4-box chunks, descending
        f32x16 q0, q1;
        SLOADCHUNK(q0, q1, bb + c * 32);
        test1(q1, 8, c * 4 + 3);                  // descending within chunk
        test1(q1, 0, c * 4 + 2);
        test1(q0, 8, c * 4 + 1);
        test1(q0, 0, c * 4 + 0);
    }

    // p0 even -> 8 B aligned float2 store, coalesced.
    *(float2*)(out + p0) = make_float2((float)idx0, (float)idx1);
}

extern "C" void kernel_launch(void* const* d_in, const int* in_sizes, int n_in,
                              void* d_out, int out_size, void* d_ws, size_t ws_size,
                              hipStream_t stream) {
    const float* points = (const float*)d_in[0];   // [B, N, 3] f32
    const float* boxes  = (const float*)d_in[1];   // [B, M, 7] f32
    float* out = (float*)d_out;                    // [B, N]    f32
    float* prep = (float*)d_ws;                    // [B*M, 8]  f32 = 16 KB

    int n_points = in_sizes[0] / 3;                // B*N = 262144
    int n_boxes  = in_sizes[1] / 7;                // B*M = 512

    int prep_blocks = (n_boxes + 255) / 256;       // 2
    prep_boxes<<<prep_blocks, 256, 0, stream>>>(boxes, prep, n_boxes);

    int main_blocks = n_points / PPB;              // 512
    pib_main<<<main_blocks, TPB, 0, stream>>>(points, prep, out);
}

// Round 10
// 19.795 us; speedup vs baseline: 1.4262x; 1.4262x over previous
//
#include <hip/hip_runtime.h>
#include <math.h>

// Problem constants (from reference setup): B=4, N=65536, M=128.
#define NPTS  65536
#define MBOX  128
#define TPB   256
#define PPT   2               // points per thread -> float2 packed math
#define PPB   (TPB * PPT)     // 512 points per block
#define CHUNK 8               // boxes per load-batch (16 ds_read_b128 in flight)

// R3's proven structure (single fused dispatch, LDS-staged box records,
// chunked uniform ds_read_b128) + packed-FP32 arithmetic: the two points'
// test math is written as float2 vector ops -> <2 x float> IR -> VOP3P
// v_pk_mul_f32 / v_pk_add_f32 on CDNA4, halving arithmetic VALU issue
// (18 scalar -> 9 pk per box). #pragma clang fp contract(off) forbids
// mul+add fusion, so per-element rounding stays mul,mul,add in rn — exactly
// the reference (and exactly R1-R8's __f*_rn code, absmax=0 every round).
// Descending m + overwrite: last write at smallest m == first containing box.
__global__ __launch_bounds__(256) void pib_fused(const float* __restrict__ points,
                                                 const float* __restrict__ boxes,
                                                 float* __restrict__ out) {
    #pragma clang fp contract(off)
    __shared__ float sraw[MBOX * 7];  // 3.5 KB raw boxes
    __shared__ float srec[MBOX * 8];  // 4.0 KB derived records

    const int blocksPerBatch = NPTS / PPB;            // 128
    int b   = blockIdx.x >> 7;
    int blk = blockIdx.x & 127;

    // Per-thread points: 6 floats = 3x float2 (8 B aligned, coalesced).
    size_t p0 = (size_t)b * NPTS + (size_t)blk * PPB + (size_t)threadIdx.x * PPT;
    const float* p = points + p0 * 3;
    float2 a01 = *(const float2*)(p);
    float2 a23 = *(const float2*)(p + 2);
    float2 a45 = *(const float2*)(p + 4);
    float2 px = make_float2(a01.x, a23.y);            // {pt0.x, pt1.x}
    float2 py = make_float2(a01.y, a45.x);            // {pt0.y, pt1.y}
    float2 pz = make_float2(a23.x, a45.y);            // {pt0.z, pt1.z}

    // Stage raw boxes, coalesced.
    const float* bsrc = boxes + (size_t)b * MBOX * 7;
    for (int i = threadIdx.x; i < MBOX * 7; i += TPB) sraw[i] = bsrc[i];
    __syncthreads();

    // Derived records {cx,cy,cz,hx,hy,hz,cos,sin}; one thread per box.
    // stride-7 LDS reads conflict-free (gcd(7,32)=1); one-time cost.
    if (threadIdx.x < MBOX) {
        const float* r = sraw + threadIdx.x * 7;
        float rz = r[6];
        float* o = srec + threadIdx.x * 8;
        o[0] = r[0]; o[1] = r[1]; o[2] = r[2];
        o[3] = 0.5f * r[3];   // exact, matches ref dims*0.5
        o[4] = 0.5f * r[4];
        o[5] = 0.5f * r[5];
        o[6] = cosf(rz);      // accurate libm: matches numpy (absmax=0 R1-R8)
        o[7] = sinf(rz);
    }
    __syncthreads();

    int idx0 = -1, idx1 = -1;

    // Packed test of one box (record in Q0,Q1) against both points.
    // float2 ops -> v_pk_*_f32; compares fold |x| as a VOP3 src modifier.
    // Rounding per element: sub; mul,mul,add; mul,mul,sub — identical to ref
    // (Y: rn(ly*cr - lx*sr) == rn(-lx*sr + ly*cr), negation is exact).
#define TESTPAIR(Q0, Q1, M)                                                     \
    do {                                                                        \
        float2 lx = px - make_float2((Q0).x, (Q0).x);                           \
        float2 ly = py - make_float2((Q0).y, (Q0).y);                           \
        float2 lz = pz - make_float2((Q0).z, (Q0).z);                           \
        float2 t0 = lx * make_float2((Q1).z, (Q1).z);  /* lx*cr */              \
        float2 t1 = ly * make_float2((Q1).w, (Q1).w);  /* ly*sr */              \
        float2 t2 = ly * make_float2((Q1).z, (Q1).z);  /* ly*cr */              \
        float2 t3 = lx * make_float2((Q1).w, (Q1).w);  /* lx*sr */              \
        float2 X = t0 + t1;                                                     \
        float2 Y = t2 - t3;                                                     \
        bool in0 = (fabsf(X.x) <= (Q0).w) & (fabsf(Y.x) <= (Q1).x) &            \
                   (fabsf(lz.x) <= (Q1).y);                                     \
        bool in1 = (fabsf(X.y) <= (Q0).w) & (fabsf(Y.y) <= (Q1).x) &            \
                   (fabsf(lz.y) <= (Q1).y);                                     \
        idx0 = in0 ? (M) : idx0;                                                \
        idx1 = in1 ? (M) : idx1;                                                \
    } while (0)

    #pragma unroll 2
    for (int base = MBOX - CHUNK; base >= 0; base -= CHUNK) {
        float4 q[2 * CHUNK];              // loop-local: unroll-2 renames = dbuf
        #pragma unroll
        for (int k = 0; k < CHUNK; ++k) {
            q[2 * k]     = ((const float4*)srec)[(base + k) * 2];     // uniform
            q[2 * k + 1] = ((const float4*)srec)[(base + k) * 2 + 1]; // -> bcast
        }
        #pragma unroll
        for (int k = CHUNK - 1; k >= 0; --k)   // descending within chunk
            TESTPAIR(q[2 * k], q[2 * k + 1], base + k);
    }
#undef TESTPAIR

    // p0 even -> 8 B aligned float2 store, coalesced.
    *(float2*)(out + p0) = make_float2((float)idx0, (float)idx1);
}

extern "C" void kernel_launch(void* const* d_in, const int* in_sizes, int n_in,
                              void* d_out, int out_size, void* d_ws, size_t ws_size,
                              hipStream_t stream) {
    const float* points = (const float*)d_in[0];   // [B, N, 3] f32
    const float* boxes  = (const float*)d_in[1];   // [B, M, 7] f32
    float* out = (float*)d_out;                    // [B, N]    f32

    int n_points = in_sizes[0] / 3;                // B*N = 262144
    int main_blocks = n_points / PPB;              // 512 = 2 blocks/CU

    pib_fused<<<main_blocks, TPB, 0, stream>>>(points, boxes, out);
}

// Round 11
// 17.255 us; speedup vs baseline: 1.6361x; 1.1472x over previous
//
#include <hip/hip_runtime.h>
#include <math.h>

// Problem constants (from reference setup): B=4, N=65536, M=128.
#define NPTS  65536
#define MBOX  128
#define TPB   256
#define WAVES 4
#define PPB   512             // points per block (shared by all 4 waves)
#define PPL   8               // points per lane
#define SLICE (MBOX / WAVES)  // 32 boxes per wave
#define CHUNK 8               // boxes per load-batch
#define SENT  999

// Box-sliced structure: R3/R10's LDS-staged records, but each wave tests only
// its 32-box slice against the block's 512 shared points. Per-wave uniform
// ds_read_b128 count drops 256 -> ~70 (the LDS return path, which scales with
// wave count, was the binding pipe in R2/R3/R10). Per-point partial first-hit
// per slice (descending overwrite), then an LDS min-combine across the 4
// slices: min over slice-partials == global first hit (slices are disjoint
// ascending index ranges). Packed f32 math (VOP3P) with contraction off:
// per-element rounding is mul,mul,add in rn — bit-identical to the reference
// and to R1-R10 (absmax=0 every passing round).
__global__ __launch_bounds__(256) void pib_sliced(const float* __restrict__ points,
                                                  const float* __restrict__ boxes,
                                                  float* __restrict__ out) {
    #pragma clang fp contract(off)
    __shared__ float sraw[MBOX * 7];     // 3.5 KB raw boxes
    __shared__ float srec[MBOX * 8];     // 4.0 KB derived records
    __shared__ int   part[WAVES * PPB];  // 8.0 KB slice partials

    const int blocksPerBatch = NPTS / PPB;   // 128
    int b    = blockIdx.x >> 7;
    int blk  = blockIdx.x & 127;
    int wv   = threadIdx.x >> 6;
    int lane = threadIdx.x & 63;

    // Stage raw boxes, coalesced.
    const float* bsrc = boxes + (size_t)b * MBOX * 7;
    for (int i = threadIdx.x; i < MBOX * 7; i += TPB) sraw[i] = bsrc[i];
    __syncthreads();

    // Derived records {cx,cy,cz,hx,hy,hz,cos,sin}; one thread per box.
    // stride-7 LDS reads conflict-free (gcd(7,32)=1); one-time cost.
    if (threadIdx.x < MBOX) {
        const float* r = sraw + threadIdx.x * 7;
        float rz = r[6];
        float* o = srec + threadIdx.x * 8;
        o[0] = r[0]; o[1] = r[1]; o[2] = r[2];
        o[3] = 0.5f * r[3];   // exact, matches ref dims*0.5
        o[4] = 0.5f * r[4];
        o[5] = 0.5f * r[5];
        o[6] = cosf(rz);      // accurate libm: matches numpy (absmax=0 R1-R10)
        o[7] = sinf(rz);
    }
    __syncthreads();

    // Lane's 8 points (same 512 points in all 4 waves; 4x redundant global
    // loads are L1/L2 hits, one-time). 24 floats = 6x float4, 16B-aligned
    // (pbase*3*4B is a multiple of 96B).
    size_t pbase = (size_t)b * NPTS + (size_t)blk * PPB + (size_t)lane * PPL;
    const float* pp = points + pbase * 3;
    float f[24];
    *(float4*)&f[0]  = *(const float4*)(pp);
    *(float4*)&f[4]  = *(const float4*)(pp + 4);
    *(float4*)&f[8]  = *(const float4*)(pp + 8);
    *(float4*)&f[12] = *(const float4*)(pp + 12);
    *(float4*)&f[16] = *(const float4*)(pp + 16);
    *(float4*)&f[20] = *(const float4*)(pp + 20);

    // 4 point-pairs in packed registers (all indices compile-time, rule #20).
    float2 PX[4], PY[4], PZ[4];
    #pragma unroll
    for (int j = 0; j < 4; ++j) {
        PX[j] = make_float2(f[6*j],     f[6*j + 3]);
        PY[j] = make_float2(f[6*j + 1], f[6*j + 4]);
        PZ[j] = make_float2(f[6*j + 2], f[6*j + 5]);
    }

    int IDX[PPL];
    #pragma unroll
    for (int k = 0; k < PPL; ++k) IDX[k] = SENT;

    const int mlo = wv * SLICE;
    #pragma unroll 2
    for (int base = mlo + SLICE - CHUNK; base >= mlo; base -= CHUNK) {
        float4 q[2 * CHUNK];              // chunk of 8 box records, batched loads
        #pragma unroll
        for (int k = 0; k < CHUNK; ++k) {
            q[2*k]   = ((const float4*)srec)[(base + k) * 2];     // uniform
            q[2*k+1] = ((const float4*)srec)[(base + k) * 2 + 1]; // -> bcast
        }
        #pragma unroll
        for (int k = CHUNK - 1; k >= 0; --k) {   // descending within slice
            const float4 Q0 = q[2*k], Q1 = q[2*k+1];
            const int M = base + k;
            #pragma unroll
            for (int j = 0; j < 4; ++j) {
                float2 lx = PX[j] - make_float2(Q0.x, Q0.x);
                float2 ly = PY[j] - make_float2(Q0.y, Q0.y);
                float2 lz = PZ[j] - make_float2(Q0.z, Q0.z);
                float2 t0 = lx * make_float2(Q1.z, Q1.z);   // lx*cr
                float2 t1 = ly * make_float2(Q1.w, Q1.w);   // ly*sr
                float2 t2 = ly * make_float2(Q1.z, Q1.z);   // ly*cr
                float2 t3 = lx * make_float2(Q1.w, Q1.w);   // lx*sr
                float2 X = t0 + t1;
                float2 Y = t2 - t3;   // rn(ly*cr - lx*sr) == rn(-lx*sr + ly*cr)
                bool in0 = (fabsf(X.x) <= Q0.w) & (fabsf(Y.x) <= Q1.x) &
                           (fabsf(lz.x) <= Q1.y);
                bool in1 = (fabsf(X.y) <= Q0.w) & (fabsf(Y.y) <= Q1.x) &
                           (fabsf(lz.y) <= Q1.y);
                IDX[2*j]     = in0 ? M : IDX[2*j];
                IDX[2*j + 1] = in1 ? M : IDX[2*j + 1];
            }
        }
    }

    // Publish slice partials: contiguous 32B per lane -> 2x ds_write_b128
    // (4-way bank aliasing at stride 32B: ~1.6x on 2 writes, negligible).
    *(int4*)&part[wv * PPB + lane * PPL]     = make_int4(IDX[0], IDX[1], IDX[2], IDX[3]);
    *(int4*)&part[wv * PPB + lane * PPL + 4] = make_int4(IDX[4], IDX[5], IDX[6], IDX[7]);
    __syncthreads();

    // Combine: thread t owns points 2t, 2t+1; min over the 4 slice partials
    // (consecutive ints -> ds_read_b64; 2-way bank aliasing = free).
    int t = threadIdx.x;
    int m0 = SENT, m1 = SENT;
    #pragma unroll
    for (int w = 0; w < WAVES; ++w) {
        m0 = min(m0, part[w * PPB + 2 * t]);
        m1 = min(m1, part[w * PPB + 2 * t + 1]);
    }
    float2 r = make_float2(m0 < SENT ? (float)m0 : -1.0f,
                           m1 < SENT ? (float)m1 : -1.0f);
    *(float2*)(out + (size_t)b * NPTS + (size_t)blk * PPB + 2 * t) = r;
}

extern "C" void kernel_launch(void* const* d_in, const int* in_sizes, int n_in,
                              void* d_out, int out_size, void* d_ws, size_t ws_size,
                              hipStream_t stream) {
    const float* points = (const float*)d_in[0];   // [B, N, 3] f32
    const float* boxes  = (const float*)d_in[1];   // [B, M, 7] f32
    float* out = (float*)d_out;                    // [B, N]    f32

    int n_points = in_sizes[0] / 3;                // B*N = 262144
    int main_blocks = n_points / PPB;              // 512 = 2 blocks/CU

    pib_sliced<<<main_blocks, TPB, 0, stream>>>(points, boxes, out);
}

// Round 12
// 15.192 us; speedup vs baseline: 1.8583x; 1.1358x over previous
//
#include <hip/hip_runtime.h>
#include <math.h>

// Problem constants (from reference setup): B=4, N=65536, M=128.
#define NPTS  65536
#define MBOX  128
#define TPB   512
#define WAVES 8
#define PPB   512             // points per block (shared by all 8 waves)
#define PPL   8               // points per lane
#define SLICE (MBOX / WAVES)  // 16 boxes per wave
#define CHUNK 4               // boxes per load-batch (8 ds_read_b128 in flight)
#define SENT  999

// R11's box-sliced structure with doubled TLP at constant LDS traffic:
// 8 waves/block x 16-box slices (per-wave ds_reads halved -> per-CU LDS box
// traffic unchanged at 512 reads), 2 blocks/CU -> 4 waves/SIMD (vs R11's 2)
// to hide ds/global latency. Prologue leaned: box records derived straight
// from global (no LDS round-trip, single barrier), point loads issued before
// the barrier. Per-point partial first-hit per slice (descending overwrite),
// LDS 8-way min-combine (slices are disjoint ascending index ranges, so min
// over partials == global first hit). Packed f32 math (VOP3P), contraction
// off: per-element rounding is mul,mul,add in rn — bit-identical to the
// reference (absmax=0 in every passing round R1-R11).
__global__ __launch_bounds__(512, 4) void pib_sliced(const float* __restrict__ points,
                                                     const float* __restrict__ boxes,
                                                     float* __restrict__ out) {
    #pragma clang fp contract(off)
    __shared__ float srec[MBOX * 8];     //  4 KB derived records
    __shared__ int   part[WAVES * PPB];  // 16 KB slice partials

    const int blocksPerBatch = NPTS / PPB;   // 128
    int b    = blockIdx.x >> 7;
    int blk  = blockIdx.x & 127;
    int wv   = threadIdx.x >> 6;
    int lane = threadIdx.x & 63;

    // Lane's 8 points, issued before the barrier so global latency hides
    // under the box-derive. All 8 waves load the same 512 points (L1 hits
    // after the first wave). 24 floats = 6x float4 (pbase*3*4B % 96 == 0).
    size_t pbase = (size_t)b * NPTS + (size_t)blk * PPB + (size_t)lane * PPL;
    const float* pp = points + pbase * 3;
    float f[24];
    *(float4*)&f[0]  = *(const float4*)(pp);
    *(float4*)&f[4]  = *(const float4*)(pp + 4);
    *(float4*)&f[8]  = *(const float4*)(pp + 8);
    *(float4*)&f[12] = *(const float4*)(pp + 12);
    *(float4*)&f[16] = *(const float4*)(pp + 16);
    *(float4*)&f[20] = *(const float4*)(pp + 20);

    // Derive box records straight from global: thread t<128 reads box t's
    // 7 floats (wave touches a contiguous 1792 B region -> L1/L2 friendly),
    // computes cos/sin (accurate libm, matches numpy: absmax=0 R1-R11).
    if (threadIdx.x < MBOX) {
        const float* r = boxes + ((size_t)b * MBOX + threadIdx.x) * 7;
        float rz = r[6];
        float* o = srec + threadIdx.x * 8;
        o[0] = r[0]; o[1] = r[1]; o[2] = r[2];
        o[3] = 0.5f * r[3];   // exact, matches ref dims*0.5
        o[4] = 0.5f * r[4];
        o[5] = 0.5f * r[5];
        o[6] = cosf(rz);
        o[7] = sinf(rz);
    }

    // 4 point-pairs in packed registers (all indices compile-time, rule #20).
    float2 PX[4], PY[4], PZ[4];
    #pragma unroll
    for (int j = 0; j < 4; ++j) {
        PX[j] = make_float2(f[6*j],     f[6*j + 3]);
        PY[j] = make_float2(f[6*j + 1], f[6*j + 4]);
        PZ[j] = make_float2(f[6*j + 2], f[6*j + 5]);
    }

    __syncthreads();

    int IDX[PPL];
    #pragma unroll
    for (int k = 0; k < PPL; ++k) IDX[k] = SENT;

    const int mlo = wv * SLICE;
    #pragma unroll
    for (int base = mlo + SLICE - CHUNK; base >= mlo; base -= CHUNK) {
        float4 q[2 * CHUNK];              // 4 box records, loads batched
        #pragma unroll
        for (int k = 0; k < CHUNK; ++k) {
            q[2*k]   = ((const float4*)srec)[(base + k) * 2];     // uniform
            q[2*k+1] = ((const float4*)srec)[(base + k) * 2 + 1]; // -> bcast
        }
        #pragma unroll
        for (int k = CHUNK - 1; k >= 0; --k) {   // descending within slice
            const float4 Q0 = q[2*k], Q1 = q[2*k+1];
            const int M = base + k;
            #pragma unroll
            for (int j = 0; j < 4; ++j) {
                float2 lx = PX[j] - make_float2(Q0.x, Q0.x);
                float2 ly = PY[j] - make_float2(Q0.y, Q0.y);
                float2 lz = PZ[j] - make_float2(Q0.z, Q0.z);
                float2 t0 = lx * make_float2(Q1.z, Q1.z);   // lx*cr
                float2 t1 = ly * make_float2(Q1.w, Q1.w);   // ly*sr
                float2 t2 = ly * make_float2(Q1.z, Q1.z);   // ly*cr
                float2 t3 = lx * make_float2(Q1.w, Q1.w);   // lx*sr
                float2 X = t0 + t1;
                float2 Y = t2 - t3;   // rn(ly*cr - lx*sr) == rn(-lx*sr + ly*cr)
                bool in0 = (fabsf(X.x) <= Q0.w) & (fabsf(Y.x) <= Q1.x) &
                           (fabsf(lz.x) <= Q1.y);
                bool in1 = (fabsf(X.y) <= Q0.w) & (fabsf(Y.y) <= Q1.x) &
                           (fabsf(lz.y) <= Q1.y);
                IDX[2*j]     = in0 ? M : IDX[2*j];
                IDX[2*j + 1] = in1 ? M : IDX[2*j + 1];
            }
        }
    }

    // Publish slice partials (one-time; write conflicts negligible).
    *(int4*)&part[wv * PPB + lane * PPL]     = make_int4(IDX[0], IDX[1], IDX[2], IDX[3]);
    *(int4*)&part[wv * PPB + lane * PPL + 4] = make_int4(IDX[4], IDX[5], IDX[6], IDX[7]);
    __syncthreads();

    // Combine: thread t owns point t; min over the 8 slice partials
    // (lanes read consecutive ints -> 2 lanes/bank = free).
    int t = threadIdx.x;
    int m0 = SENT;
    #pragma unroll
    for (int w = 0; w < WAVES; ++w) m0 = min(m0, part[w * PPB + t]);
    out[(size_t)b * NPTS + (size_t)blk * PPB + t] = m0 < SENT ? (float)m0 : -1.0f;
}

extern "C" void kernel_launch(void* const* d_in, const int* in_sizes, int n_in,
                              void* d_out, int out_size, void* d_ws, size_t ws_size,
                              hipStream_t stream) {
    const float* points = (const float*)d_in[0];   // [B, N, 3] f32
    const float* boxes  = (const float*)d_in[1];   // [B, M, 7] f32
    float* out = (float*)d_out;                    // [B, N]    f32

    int n_points = in_sizes[0] / 3;                // B*N = 262144
    int main_blocks = n_points / PPB;              // 512 = 2 blocks/CU

    pib_sliced<<<main_blocks, TPB, 0, stream>>>(points, boxes, out);
}